// Round 6
// baseline (169.029 us; speedup 1.0000x reference)
//
#include <hip/hip_runtime.h>

// GraphAttentionLayer: B=1, N=4096, F=256, H=8, U=64
//
// e_src cancels in softmax over j =>
//   out[i, u*8+h] = relu( (A @ (w*h))[i, h*64+u] / (A @ w)[i, h] ),  w = exp(e_dst)
// => ONE dense GEMM  C = A(4096x4096) x G(4096x544), G = [w*h (512) | w (8) | 0 (24)]
//
// R9 (3rd submit; rounds 4-5 were container/infra failures, source audited
// clean: bounds, uniform barriers, LDS/VGPR budgets all verified):
// L1-reuse restructure of k_gemm. Evidence R5-R8: perf tracks per-wave
// load ILP (R7 best w/ 4 in-flight B-loads/step; R8's 2 regressed), not
// occupancy (R6) nor MFMA:load ratio (R8).
//  k_gemm: block = 64 rows x 8 n-tiles, 8 waves = (mr 2 m-tiles) x (nc 4
//  n-pairs). Wave: 1 m-tile x n-pair {2nc,2nc+1} -> SAME per-wave shape as
//  R7 (4 B-loads + 2 A ds_reads + 4 MFMA per step), but wave-pairs (mr=0/1)
//  read identical B addresses -> L1 hits; per-block distinct B halved.
//  Den: wave covers ksub {4nc..4nc+3} for its m-tile (4 MFMA/chunk, nh==0
//  blocks), LDS-reduced over nc. Grid 64 strips x 2 nh x 2 z = 256 blocks,
//  XCD-pinned z-slabs, plain stores. k_hg/k_out unchanged (isolate variable).
//
// Gtp layout (HW-verified R4): tile (tk=k>>4, nt=n>>5), id=tk*17+nt, 1024 B:
//   u16[ id*512 + ((n&31) + 32*((k&15)>>3))*8 + (k&7) ]
// B-frag(lane) = 16 B at id*1024 + lane*16.
//
// ws: P (2 slabs of 4096 x 520 fp32 = 17,039,360 B) | Gtp @17039360 (4352*1024 B)

typedef unsigned short u16;
typedef unsigned int   u32;
typedef __attribute__((ext_vector_type(8)))  short  short8;    // 8 bf16 (4 VGPR)
typedef __attribute__((ext_vector_type(16))) float  floatx16;  // 32x32 MFMA acc
typedef __attribute__((ext_vector_type(8)))  unsigned short u16x8;
typedef __attribute__((ext_vector_type(4)))  unsigned short u16x4;

__device__ __forceinline__ u16 f2bf(float x) {
  u32 u = __float_as_uint(x);
  u += 0x7fffu + ((u >> 16) & 1u);   // RNE
  return (u16)(u >> 16);
}

__device__ __forceinline__ void async_ld16(const void* g, void* l) {
  __builtin_amdgcn_global_load_lds((const __attribute__((address_space(1))) void*)g,
                                   (__attribute__((address_space(3))) void*)l,
                                   16, 0, 0);
}

// ---------------------------------------------------------------------------
// Kernel 1: h = X@W (fp32, exact), e_dst -> w = exp, write Gtp (B-frag layout).
// Block: 32 j-rows x 128 c-cols (2 whole heads => e-sums block-local).
// Thread: 4j x 4c. K in 4 single-buffered chunks of 64 (W async->LDS, X
// transposed). Grid (128, 4) = 512 blocks = 2/CU.  (R5-proven version.)
// ---------------------------------------------------------------------------
__global__ __launch_bounds__(256) void k_hg(const float* __restrict__ X,
                                            const float* __restrict__ W,
                                            const float* __restrict__ av,
                                            u16* __restrict__ Gtp) {
  __shared__ __align__(16) float Wc[64 * 128];   // 32 KB
  __shared__ __align__(16) float xs[64 * 36];    // 9 KB (pad 36 breaks stride)
  __shared__ float eL[64];
  __shared__ float w8L[64];
  const int t  = threadIdx.x;
  const int j0 = blockIdx.x * 32;
  const int y  = blockIdx.y;           // heads 2y, 2y+1
  const int c0 = y * 128;
  const int cq = t & 31, tj = t >> 5;

  if (t < 64) eL[t] = 0.f;

  float acc[4][4];
#pragma unroll
  for (int a = 0; a < 4; ++a)
#pragma unroll
    for (int b = 0; b < 4; ++b) acc[a][b] = 0.f;

  const int xjj = t >> 3, xoff = (t & 7) * 8;

  for (int cc = 0; cc < 4; ++cc) {
    // stage W chunk (64 k x 128 c) via async global->LDS
#pragma unroll
    for (int l = 0; l < 8; ++l) {
      int id = l * 256 + t;
      int kk = id >> 5, ch = id & 31;
      async_ld16(W + (size_t)(cc * 64 + kk) * 512 + c0 + ch * 4,
                 (char*)&Wc[0] + (size_t)(l * 256 + (t & 192)) * 16);
    }
    // stage X chunk transposed: xs[k][j]
    {
      const float* xp = X + (size_t)(j0 + xjj) * 256 + cc * 64 + xoff;
      float4 v0 = *(const float4*)xp;
      float4 v1 = *(const float4*)(xp + 4);
      xs[(xoff + 0) * 36 + xjj] = v0.x; xs[(xoff + 1) * 36 + xjj] = v0.y;
      xs[(xoff + 2) * 36 + xjj] = v0.z; xs[(xoff + 3) * 36 + xjj] = v0.w;
      xs[(xoff + 4) * 36 + xjj] = v1.x; xs[(xoff + 5) * 36 + xjj] = v1.y;
      xs[(xoff + 6) * 36 + xjj] = v1.z; xs[(xoff + 7) * 36 + xjj] = v1.w;
    }
    __syncthreads();
#pragma unroll 4
    for (int kk = 0; kk < 64; ++kk) {
      float4 w4 = *(const float4*)(&Wc[kk * 128 + cq * 4]);
      float4 xa = *(const float4*)(&xs[kk * 36 + tj * 4]);   // broadcast
      acc[0][0] += xa.x * w4.x; acc[0][1] += xa.x * w4.y; acc[0][2] += xa.x * w4.z; acc[0][3] += xa.x * w4.w;
      acc[1][0] += xa.y * w4.x; acc[1][1] += xa.y * w4.y; acc[1][2] += xa.y * w4.z; acc[1][3] += xa.y * w4.w;
      acc[2][0] += xa.z * w4.x; acc[2][1] += xa.z * w4.y; acc[2][2] += xa.z * w4.z; acc[2][3] += xa.z * w4.w;
      acc[3][0] += xa.w * w4.x; acc[3][1] += xa.w * w4.y; acc[3][2] += xa.w * w4.z; acc[3][3] += xa.w * w4.w;
    }
    __syncthreads();
  }

  // e_dst partials (2 block-local heads)
  const int lh = cq >> 4;
  {
    const float4 ad = *(const float4*)(av + 64 + (cq & 15) * 4);
#pragma unroll
    for (int jv = 0; jv < 4; ++jv) {
      float ep = acc[jv][0] * ad.x + acc[jv][1] * ad.y + acc[jv][2] * ad.z + acc[jv][3] * ad.w;
      atomicAdd(&eL[(tj * 4 + jv) * 2 + lh], ep);
    }
  }
  __syncthreads();
  if (t < 64) {
    float e = fminf(30.f, fmaxf(-30.f, eL[t]));
    w8L[t] = __expf(e);
  }
  __syncthreads();

  // scaled bf16 stores in B-frag layout
  const int tk  = (j0 >> 4) + (tj >> 2);     // j>>4 for j = j0 + tj*4 + jv
  const int khh = (tj >> 1) & 1;             // (j&15)>>3
  const int jlo = (tj & 1) * 4;              // j&7 base
#pragma unroll
  for (int cv = 0; cv < 4; ++cv) {
    int n  = c0 + cq * 4 + cv;
    int nt = n >> 5;
    u16x4 o;
#pragma unroll
    for (int jv = 0; jv < 4; ++jv)
      o[jv] = f2bf(acc[jv][cv] * w8L[(tj * 4 + jv) * 2 + lh]);
    *(u16x4*)(Gtp + (size_t)(tk * 17 + nt) * 512 + ((n & 31) + 32 * khh) * 8 + jlo) = o;
  }
  // den rows (n = 512 + h, this block's 2 heads x 32 rows)
  if (t < 64) {
    int jj = t >> 1, lh2 = t & 1, h = 2 * y + lh2, j = j0 + jj;
    Gtp[(size_t)((j >> 4) * 17 + 16) * 512 + (h + 32 * ((jj & 15) >> 3)) * 8 + (jj & 7)] =
        f2bf(w8L[jj * 2 + lh2]);
  }
  // zero pad (n in [520,544)): slots [8,32) and [40,64) of tile nt=16; y==3 does it
  if (y == 3 && t < 96) {
    int tk2 = t / 48, r = t - tk2 * 48;
    int slot = (r < 24) ? (8 + r) : (16 + r);
    u16x8 z = {0, 0, 0, 0, 0, 0, 0, 0};
    *(u16x8*)(Gtp + (size_t)(((j0 >> 4) + tk2) * 17 + 16) * 512 + slot * 8) = z;
  }
}

// ---------------------------------------------------------------------------
// Kernel 2: Pz = A(fp32,{0,1}) x G^T via 32x32x16 bf16 MFMA, PLAIN stores.
// Block: 512 threads = 8 waves = (mr in {0,1} m-tile) x (nc in 0..3 n-pair).
// Wave: 1 m-tile x n-tiles {nh*8+2nc, +1}. Per ds-step: 4 independent
// B-loads + 2 A ds_reads + 4 MFMA (R7-proven ILP shape); wave-pairs sharing
// nc read identical B addresses -> L1 reuse. Den (nh==0): wave covers ksub
// {4nc..4nc+3} of its m-tile per chunk; LDS-reduced over nc at the end.
// Z=2 (K=2048, 8 chunks of 256), XOR-swizzled dbuf LDS A. Grid 256 blocks;
// XCD decode pins each z's 2.23 MB Gtp k-slab to 4 XCDs.
// ---------------------------------------------------------------------------
__global__ __launch_bounds__(512, 2) void k_gemm(const float* __restrict__ A,
                                                 const u16* __restrict__ Gtp,
                                                 float* __restrict__ P) {
  __shared__ __align__(16) u16 As[2][64 * 256];  // 2 x 32 KB
  const int t    = threadIdx.x;
  const int bid  = blockIdx.x;
  const int xcd  = bid & 7, seq = bid >> 3;      // HW round-robins blockIdx%8 -> XCD
  const int z    = xcd >> 2;                     // k-slice 0..1
  const int idx  = ((xcd & 3) << 5) + seq;       // 0..127 per z
  const int strip = idx >> 1;                    // 0..63
  const int nh   = idx & 1;                      // n-half
  const int i0   = strip * 64;
  const int kt0  = z * 2048;
  const int w    = t >> 6, lane = t & 63;
  const int ml   = lane & 31, kh = lane >> 5;
  const int mr   = w & 1;                        // m-tile
  const int nc   = w >> 1;                       // n-pair
  const int nt0  = nh * 8 + 2 * nc;
  const int nt1  = nt0 + 1;

  floatx16 c0, c1, dn;
#pragma unroll
  for (int r = 0; r < 16; ++r) { c0[r] = 0.f; c1[r] = 0.f; dn[r] = 0.f; }

  // A staging: thread -> row ar (0..63), q-th float4 at k = (t&7)*4 + q*32
  const int ar  = t >> 3;
  const int af  = (t & 7) * 4;
  const float* pa = A + (size_t)(i0 + ar) * 4096 + kt0 + af;
  const int sbase = ar * 256 + (t & 1) * 4;   // + swizzled granule*8
  const int scb   = (t & 7) >> 1;             // granule = q*4 + scb
  const int arx   = ar & 7;

  // A-frag reads: rows mr*32 + ml, granule g -> physical g^(ml&7)
  const int arow = (mr * 32 + ml) * 256;
  const int mx   = ml & 7;

  float4 areg[8];
#pragma unroll
  for (int q = 0; q < 8; ++q) areg[q] = *(const float4*)(pa + q * 32);
#pragma unroll
  for (int q = 0; q < 8; ++q) {
    u16x4 v = {f2bf(areg[q].x), f2bf(areg[q].y), f2bf(areg[q].z), f2bf(areg[q].w)};
    *(u16x4*)(&As[0][sbase + ((q * 4 + scb) ^ arx) * 8]) = v;
  }
  __syncthreads();

  for (int cc = 0; cc < 8; ++cc) {
    const int cb = cc & 1;
    if (cc < 7) {                    // prefetch next chunk early (hidden by compute)
#pragma unroll
      for (int q = 0; q < 8; ++q)
        areg[q] = *(const float4*)(pa + (cc + 1) * 256 + q * 32);
    }
    const int ktb = (kt0 >> 4) + cc * 16;
#pragma unroll 2
    for (int ds = 0; ds < 8; ++ds) {
      short8 b00 = *(const short8*)(Gtp + (size_t)((ktb + ds * 2) * 17 + nt0) * 512 + lane * 8);
      short8 b01 = *(const short8*)(Gtp + (size_t)((ktb + ds * 2) * 17 + nt1) * 512 + lane * 8);
      short8 b10 = *(const short8*)(Gtp + (size_t)((ktb + ds * 2 + 1) * 17 + nt0) * 512 + lane * 8);
      short8 b11 = *(const short8*)(Gtp + (size_t)((ktb + ds * 2 + 1) * 17 + nt1) * 512 + lane * 8);
      short8 a0 = *(const short8*)(&As[cb][arow + ((ds * 4 + kh) ^ mx) * 8]);
      short8 a1 = *(const short8*)(&As[cb][arow + ((ds * 4 + 2 + kh) ^ mx) * 8]);
      c0 = __builtin_amdgcn_mfma_f32_32x32x16_bf16(a0, b00, c0, 0, 0, 0);
      c1 = __builtin_amdgcn_mfma_f32_32x32x16_bf16(a0, b01, c1, 0, 0, 0);
      c0 = __builtin_amdgcn_mfma_f32_32x32x16_bf16(a1, b10, c0, 0, 0, 0);
      c1 = __builtin_amdgcn_mfma_f32_32x32x16_bf16(a1, b11, c1, 0, 0, 0);
    }
    // den tile 16: wave covers ksub {4nc..4nc+3} of its m-tile (nh==0 only)
    if (nh == 0) {
#pragma unroll
      for (int q = 0; q < 4; ++q) {
        int ksub = nc * 4 + q;
        short8 e = *(const short8*)(Gtp + (size_t)((ktb + ksub) * 17 + 16) * 512 + lane * 8);
        short8 a = *(const short8*)(&As[cb][arow + ((ksub * 2 + kh) ^ mx) * 8]);
        dn = __builtin_amdgcn_mfma_f32_32x32x16_bf16(a, e, dn, 0, 0, 0);
      }
    }
    if (cc < 7) {
      __syncthreads();               // readers of other buffer done
#pragma unroll
      for (int q = 0; q < 8; ++q) {
        u16x4 v = {f2bf(areg[q].x), f2bf(areg[q].y), f2bf(areg[q].z), f2bf(areg[q].w)};
        *(u16x4*)(&As[cb ^ 1][sbase + ((q * 4 + scb) ^ arx) * 8]) = v;
      }
      __syncthreads();               // writes visible
    }
  }

  // ---- epilogue: plain stores to slab z (no atomics) ----
  float* Pz = P + (size_t)z * (4096 * 520);
  const int col0 = nt0 * 32 + ml;
  // C/D layout: col = lane&31, row = (r&3) + 8*(r>>2) + 4*(lane>>5)
#pragma unroll
  for (int r = 0; r < 16; ++r) {
    int row = i0 + mr * 32 + 4 * kh + (r & 3) + 8 * (r >> 2);
    Pz[(size_t)row * 520 + col0]      = c0[r];
    Pz[(size_t)row * 520 + col0 + 32] = c1[r];
  }

  // den cols 512..519: reduce dn over nc via LDS (As[0] free: last read cc==6)
  if (nh == 0) {
    float* dred = (float*)&As[0][0];   // (mr*4+nc) x 32 rows x 8 cols = 8 KB
    if (ml < 8) {
#pragma unroll
      for (int r = 0; r < 16; ++r) {
        int row32 = 4 * kh + (r & 3) + 8 * (r >> 2);
        dred[((mr * 4 + nc) * 32 + row32) * 8 + ml] = dn[r];
      }
    }
    __syncthreads();
    {
      int row = t >> 3, c = t & 7;   // 512 threads = 64 rows x 8 cols
      int mrr = row >> 5, r32 = row & 31;
      float s = 0.f;
#pragma unroll
      for (int q = 0; q < 4; ++q) s += dred[((mrr * 4 + q) * 32 + r32) * 8 + c];
      Pz[(size_t)(i0 + row) * 520 + 512 + c] = s;
    }
  }
}

// ---------------------------------------------------------------------------
// Kernel 3: out[i, u*8+h] = relu( SUMz Pz[i][h*64+u] / SUMz Pz[i][512+h] ).
// 2 rows/block, 2048 blocks.
// ---------------------------------------------------------------------------
__global__ __launch_bounds__(256) void k_out(const float* __restrict__ P,
                                             float* __restrict__ out) {
  __shared__ float ps[2][520];
  const size_t SL = (size_t)4096 * 520;
  const int t    = threadIdx.x;
  const int half = t >> 7, lt = t & 127;
  const int i    = blockIdx.x * 2 + half;
  const float* pr = P + (size_t)i * 520;
  for (int q = lt; q < 520; q += 128) ps[half][q] = pr[q] + pr[SL + q];
  __syncthreads();
  for (int c = lt; c < 512; c += 128) {           // c = u*8 + h
    int u = c >> 3, hd = c & 7;
    float o = ps[half][hd * 64 + u] / ps[half][512 + hd];
    out[(size_t)i * 512 + c] = fmaxf(o, 0.f);
  }
}

extern "C" void kernel_launch(void* const* d_in, const int* in_sizes, int n_in,
                              void* d_out, int out_size, void* d_ws, size_t ws_size,
                              hipStream_t stream) {
  const float* X  = (const float*)d_in[0];
  const float* A  = (const float*)d_in[1];
  const float* W  = (const float*)d_in[2];
  const float* av = (const float*)d_in[3];
  float* out = (float*)d_out;
  char*  ws  = (char*)d_ws;

  float* P   = (float*)ws;                 // 2 slabs x 4096 x 520 fp32
  u16*   Gtp = (u16*)(ws + 17039360);      // 256*17 tiles * 1024 B

  k_hg<<<dim3(128, 4), 256, 0, stream>>>(X, W, av, Gtp);
  k_gemm<<<256, 512, 0, stream>>>(A, Gtp, P);
  k_out<<<2048, 256, 0, stream>>>(P, out);
}

// Round 7
// 152.700 us; speedup vs baseline: 1.1069x; 1.1069x over previous
//
#include <hip/hip_runtime.h>

// GraphAttentionLayer: B=1, N=4096, F=256, H=8, U=64
//
// e_src cancels in softmax over j =>
//   out[i, u*8+h] = relu( (A @ (w*h))[i, h*64+u] / (A @ w)[i, h] ),  w = exp(e_dst)
// => ONE dense GEMM  C = A(4096x4096) x G(4096x544), G = [w*h (512) | w (8) | 0 (24)]
//
// R10: clean TLP test. R5-R9 separated the levers: per-wave load ILP matters
// (R8/R9 regressions), TLP never tested without a VGPR squeeze (R6 confound).
//  k_gemm: BM=32, N-split (nh) -> block = 32 rows x 8 n-tiles (+den on nh=0).
//  Wave owns ONE n-tile, 4 k-tiles per ds-iter -> R7's exact ILP shape
//  (4 indep B-loads + 4 A ds_reads + 4 MFMA), but only 1-2 acc chains ->
//  fits 128 unified regs -> launch_bounds(512,4) = 2 blk/CU, 4 waves/SIMD.
//  Grid 128 strips x 2 nh x 2 z = 512 blocks; nh halves write disjoint P
//  cols (ws unchanged); z still XCD-pinned. Plain stores. k_hg/k_out frozen.
//
// Gtp layout (HW-verified R4): tile (tk=k>>4, nt=n>>5), id=tk*17+nt, 1024 B:
//   u16[ id*512 + ((n&31) + 32*((k&15)>>3))*8 + (k&7) ]
// B-frag(lane) = 16 B at id*1024 + lane*16.
//
// ws: P (2 slabs of 4096 x 520 fp32 = 17,039,360 B) | Gtp @17039360 (4352*1024 B)

typedef unsigned short u16;
typedef unsigned int   u32;
typedef __attribute__((ext_vector_type(8)))  short  short8;    // 8 bf16 (4 VGPR)
typedef __attribute__((ext_vector_type(16))) float  floatx16;  // 32x32 MFMA acc
typedef __attribute__((ext_vector_type(8)))  unsigned short u16x8;
typedef __attribute__((ext_vector_type(4)))  unsigned short u16x4;

__device__ __forceinline__ u16 f2bf(float x) {
  u32 u = __float_as_uint(x);
  u += 0x7fffu + ((u >> 16) & 1u);   // RNE
  return (u16)(u >> 16);
}

__device__ __forceinline__ void async_ld16(const void* g, void* l) {
  __builtin_amdgcn_global_load_lds((const __attribute__((address_space(1))) void*)g,
                                   (__attribute__((address_space(3))) void*)l,
                                   16, 0, 0);
}

// ---------------------------------------------------------------------------
// Kernel 1: h = X@W (fp32, exact), e_dst -> w = exp, write Gtp (B-frag layout).
// Block: 32 j-rows x 128 c-cols (2 whole heads => e-sums block-local).
// Thread: 4j x 4c. K in 4 single-buffered chunks of 64 (W async->LDS, X
// transposed). Grid (128, 4) = 512 blocks = 2/CU.  (R5-proven version.)
// ---------------------------------------------------------------------------
__global__ __launch_bounds__(256) void k_hg(const float* __restrict__ X,
                                            const float* __restrict__ W,
                                            const float* __restrict__ av,
                                            u16* __restrict__ Gtp) {
  __shared__ __align__(16) float Wc[64 * 128];   // 32 KB
  __shared__ __align__(16) float xs[64 * 36];    // 9 KB (pad 36 breaks stride)
  __shared__ float eL[64];
  __shared__ float w8L[64];
  const int t  = threadIdx.x;
  const int j0 = blockIdx.x * 32;
  const int y  = blockIdx.y;           // heads 2y, 2y+1
  const int c0 = y * 128;
  const int cq = t & 31, tj = t >> 5;

  if (t < 64) eL[t] = 0.f;

  float acc[4][4];
#pragma unroll
  for (int a = 0; a < 4; ++a)
#pragma unroll
    for (int b = 0; b < 4; ++b) acc[a][b] = 0.f;

  const int xjj = t >> 3, xoff = (t & 7) * 8;

  for (int cc = 0; cc < 4; ++cc) {
    // stage W chunk (64 k x 128 c) via async global->LDS
#pragma unroll
    for (int l = 0; l < 8; ++l) {
      int id = l * 256 + t;
      int kk = id >> 5, ch = id & 31;
      async_ld16(W + (size_t)(cc * 64 + kk) * 512 + c0 + ch * 4,
                 (char*)&Wc[0] + (size_t)(l * 256 + (t & 192)) * 16);
    }
    // stage X chunk transposed: xs[k][j]
    {
      const float* xp = X + (size_t)(j0 + xjj) * 256 + cc * 64 + xoff;
      float4 v0 = *(const float4*)xp;
      float4 v1 = *(const float4*)(xp + 4);
      xs[(xoff + 0) * 36 + xjj] = v0.x; xs[(xoff + 1) * 36 + xjj] = v0.y;
      xs[(xoff + 2) * 36 + xjj] = v0.z; xs[(xoff + 3) * 36 + xjj] = v0.w;
      xs[(xoff + 4) * 36 + xjj] = v1.x; xs[(xoff + 5) * 36 + xjj] = v1.y;
      xs[(xoff + 6) * 36 + xjj] = v1.z; xs[(xoff + 7) * 36 + xjj] = v1.w;
    }
    __syncthreads();
#pragma unroll 4
    for (int kk = 0; kk < 64; ++kk) {
      float4 w4 = *(const float4*)(&Wc[kk * 128 + cq * 4]);
      float4 xa = *(const float4*)(&xs[kk * 36 + tj * 4]);   // broadcast
      acc[0][0] += xa.x * w4.x; acc[0][1] += xa.x * w4.y; acc[0][2] += xa.x * w4.z; acc[0][3] += xa.x * w4.w;
      acc[1][0] += xa.y * w4.x; acc[1][1] += xa.y * w4.y; acc[1][2] += xa.y * w4.z; acc[1][3] += xa.y * w4.w;
      acc[2][0] += xa.z * w4.x; acc[2][1] += xa.z * w4.y; acc[2][2] += xa.z * w4.z; acc[2][3] += xa.z * w4.w;
      acc[3][0] += xa.w * w4.x; acc[3][1] += xa.w * w4.y; acc[3][2] += xa.w * w4.z; acc[3][3] += xa.w * w4.w;
    }
    __syncthreads();
  }

  // e_dst partials (2 block-local heads)
  const int lh = cq >> 4;
  {
    const float4 ad = *(const float4*)(av + 64 + (cq & 15) * 4);
#pragma unroll
    for (int jv = 0; jv < 4; ++jv) {
      float ep = acc[jv][0] * ad.x + acc[jv][1] * ad.y + acc[jv][2] * ad.z + acc[jv][3] * ad.w;
      atomicAdd(&eL[(tj * 4 + jv) * 2 + lh], ep);
    }
  }
  __syncthreads();
  if (t < 64) {
    float e = fminf(30.f, fmaxf(-30.f, eL[t]));
    w8L[t] = __expf(e);
  }
  __syncthreads();

  // scaled bf16 stores in B-frag layout
  const int tk  = (j0 >> 4) + (tj >> 2);     // j>>4 for j = j0 + tj*4 + jv
  const int khh = (tj >> 1) & 1;             // (j&15)>>3
  const int jlo = (tj & 1) * 4;              // j&7 base
#pragma unroll
  for (int cv = 0; cv < 4; ++cv) {
    int n  = c0 + cq * 4 + cv;
    int nt = n >> 5;
    u16x4 o;
#pragma unroll
    for (int jv = 0; jv < 4; ++jv)
      o[jv] = f2bf(acc[jv][cv] * w8L[(tj * 4 + jv) * 2 + lh]);
    *(u16x4*)(Gtp + (size_t)(tk * 17 + nt) * 512 + ((n & 31) + 32 * khh) * 8 + jlo) = o;
  }
  // den rows (n = 512 + h, this block's 2 heads x 32 rows)
  if (t < 64) {
    int jj = t >> 1, lh2 = t & 1, h = 2 * y + lh2, j = j0 + jj;
    Gtp[(size_t)((j >> 4) * 17 + 16) * 512 + (h + 32 * ((jj & 15) >> 3)) * 8 + (jj & 7)] =
        f2bf(w8L[jj * 2 + lh2]);
  }
  // zero pad (n in [520,544)): slots [8,32) and [40,64) of tile nt=16; y==3 does it
  if (y == 3 && t < 96) {
    int tk2 = t / 48, r = t - tk2 * 48;
    int slot = (r < 24) ? (8 + r) : (16 + r);
    u16x8 z = {0, 0, 0, 0, 0, 0, 0, 0};
    *(u16x8*)(Gtp + (size_t)(((j0 >> 4) + tk2) * 17 + 16) * 512 + slot * 8) = z;
  }
}

// ---------------------------------------------------------------------------
// Kernel 2: Pz = A(fp32,{0,1}) x G^T via 32x32x16 bf16 MFMA, PLAIN stores.
// Block: 512 threads = 8 waves, BM=32, N-split: nh=0 -> n-tiles 0..7 + den,
// nh=1 -> n-tiles 8..15. Wave w owns n-tile nh*8+w; per ds-iter: 4 indep
// B-loads (k-tiles 4ds..4ds+3) + 4 A ds_reads + 4 MFMA (R7 ILP shape, 1 acc
// chain). Den (nh==0): wave covers k-tiles {2w,2w+1}/chunk, LDS-reduced.
// Z=2 (K=2048, 8 chunks of 256), XOR-swizzled dbuf LDS A (2x16 KB).
// Grid 512 = 2 blk/CU, launch_bounds(512,4) -> 4 waves/SIMD (the TLP test);
// XCD decode keeps z per-XCD (L2-resident 2.23 MB Gtp k-slab).
// ---------------------------------------------------------------------------
__global__ __launch_bounds__(512, 4) void k_gemm(const float* __restrict__ A,
                                                 const u16* __restrict__ Gtp,
                                                 float* __restrict__ P) {
  __shared__ __align__(16) u16 As[2][32 * 256];  // 2 x 16 KB
  const int t    = threadIdx.x;
  const int bid  = blockIdx.x;
  const int xcd  = bid & 7, seq = bid >> 3;      // HW round-robins blockIdx%8 -> XCD
  const int z    = xcd >> 2;                     // k-slice, constant per XCD
  const int idx  = ((xcd & 3) << 6) + seq;       // 0..255 per z
  const int strip = idx >> 1;                    // 0..127
  const int nh   = idx & 1;                      // n-half
  const int i0   = strip * 32;
  const int kt0  = z * 2048;
  const int w    = t >> 6, lane = t & 63;
  const int ml   = lane & 31, kh = lane >> 5;
  const int nt   = nh * 8 + w;                   // this wave's n-tile

  floatx16 c0, dn;
#pragma unroll
  for (int r = 0; r < 16; ++r) { c0[r] = 0.f; dn[r] = 0.f; }

  // A staging (R7 verbatim): thread -> row ar (0..31), q-th float4 at
  // k = (t&15)*4 + q*64
  const int ar  = t >> 4;
  const int af  = (t & 15) * 4;
  const float* pa = A + (size_t)(i0 + ar) * 4096 + kt0 + af;
  const int sbase = ar * 256 + (t & 1) * 4;   // + swizzled granule*8
  const int scb   = (t & 15) >> 1;            // granule = q*8 + scb
  const int arx   = ar & 7;

  // A-frag reads: row m = ml, granule g -> physical g^(ml&7); k-tile j <-> granule 2j+kh
  const int arow = ml * 256;
  const int mx   = ml & 7;

  float4 areg[4];
#pragma unroll
  for (int q = 0; q < 4; ++q) areg[q] = *(const float4*)(pa + q * 64);
#pragma unroll
  for (int q = 0; q < 4; ++q) {
    u16x4 v = {f2bf(areg[q].x), f2bf(areg[q].y), f2bf(areg[q].z), f2bf(areg[q].w)};
    *(u16x4*)(&As[0][sbase + ((q * 8 + scb) ^ arx) * 8]) = v;
  }
  __syncthreads();

  for (int cc = 0; cc < 8; ++cc) {
    const int cb = cc & 1;
    if (cc < 7) {                    // prefetch next chunk early (hidden by compute)
#pragma unroll
      for (int q = 0; q < 4; ++q)
        areg[q] = *(const float4*)(pa + (cc + 1) * 256 + q * 64);
    }
    const int ktb = (kt0 >> 4) + cc * 16;
#pragma unroll 2
    for (int ds = 0; ds < 4; ++ds) {
      short8 b0 = *(const short8*)(Gtp + (size_t)((ktb + ds * 4 + 0) * 17 + nt) * 512 + lane * 8);
      short8 b1 = *(const short8*)(Gtp + (size_t)((ktb + ds * 4 + 1) * 17 + nt) * 512 + lane * 8);
      short8 b2 = *(const short8*)(Gtp + (size_t)((ktb + ds * 4 + 2) * 17 + nt) * 512 + lane * 8);
      short8 b3 = *(const short8*)(Gtp + (size_t)((ktb + ds * 4 + 3) * 17 + nt) * 512 + lane * 8);
      short8 a0 = *(const short8*)(&As[cb][arow + ((ds * 8 + 0 + kh) ^ mx) * 8]);
      short8 a1 = *(const short8*)(&As[cb][arow + ((ds * 8 + 2 + kh) ^ mx) * 8]);
      short8 a2 = *(const short8*)(&As[cb][arow + ((ds * 8 + 4 + kh) ^ mx) * 8]);
      short8 a3 = *(const short8*)(&As[cb][arow + ((ds * 8 + 6 + kh) ^ mx) * 8]);
      c0 = __builtin_amdgcn_mfma_f32_32x32x16_bf16(a0, b0, c0, 0, 0, 0);
      c0 = __builtin_amdgcn_mfma_f32_32x32x16_bf16(a1, b1, c0, 0, 0, 0);
      c0 = __builtin_amdgcn_mfma_f32_32x32x16_bf16(a2, b2, c0, 0, 0, 0);
      c0 = __builtin_amdgcn_mfma_f32_32x32x16_bf16(a3, b3, c0, 0, 0, 0);
    }
    // den tile 16: wave covers k-tiles {2w, 2w+1} of this chunk (nh==0 only)
    if (nh == 0) {
      short8 e0 = *(const short8*)(Gtp + (size_t)((ktb + w * 2) * 17 + 16) * 512 + lane * 8);
      short8 e1 = *(const short8*)(Gtp + (size_t)((ktb + w * 2 + 1) * 17 + 16) * 512 + lane * 8);
      short8 a0 = *(const short8*)(&As[cb][arow + ((w * 4 + kh) ^ mx) * 8]);
      short8 a1 = *(const short8*)(&As[cb][arow + ((w * 4 + 2 + kh) ^ mx) * 8]);
      dn = __builtin_amdgcn_mfma_f32_32x32x16_bf16(a0, e0, dn, 0, 0, 0);
      dn = __builtin_amdgcn_mfma_f32_32x32x16_bf16(a1, e1, dn, 0, 0, 0);
    }
    if (cc < 7) {
      __syncthreads();               // readers of other buffer done
#pragma unroll
      for (int q = 0; q < 4; ++q) {
        u16x4 v = {f2bf(areg[q].x), f2bf(areg[q].y), f2bf(areg[q].z), f2bf(areg[q].w)};
        *(u16x4*)(&As[cb ^ 1][sbase + ((q * 8 + scb) ^ arx) * 8]) = v;
      }
      __syncthreads();               // writes visible
    }
  }

  // ---- epilogue: plain stores to slab z (no atomics) ----
  float* Pz = P + (size_t)z * (4096 * 520);
  const int col0 = nt * 32 + ml;
  // C/D layout: col = lane&31, row = (r&3) + 8*(r>>2) + 4*(lane>>5)
#pragma unroll
  for (int r = 0; r < 16; ++r) {
    int row = i0 + 4 * kh + (r & 3) + 8 * (r >> 2);
    Pz[(size_t)row * 520 + col0] = c0[r];
  }

  // den cols 512..519: reduce dn across the 8 waves via LDS (As[0] free:
  // last read in chunk cc==6, all waves past that barrier).
  if (nh == 0) {
    float* dred = (float*)&As[0][0];   // 8 waves x 32 rows x 8 cols = 8 KB
    if (ml < 8) {
#pragma unroll
      for (int r = 0; r < 16; ++r) {
        int row32 = 4 * kh + (r & 3) + 8 * (r >> 2);
        dred[(w * 32 + row32) * 8 + ml] = dn[r];
      }
    }
    __syncthreads();
    if (t < 256) {
      int row = t >> 3, c = t & 7;   // 32 rows x 8 cols
      float s = 0.f;
#pragma unroll
      for (int ww = 0; ww < 8; ++ww) s += dred[(ww * 32 + row) * 8 + c];
      Pz[(size_t)(i0 + row) * 520 + 512 + c] = s;
    }
  }
}

// ---------------------------------------------------------------------------
// Kernel 3: out[i, u*8+h] = relu( SUMz Pz[i][h*64+u] / SUMz Pz[i][512+h] ).
// 2 rows/block, 2048 blocks.
// ---------------------------------------------------------------------------
__global__ __launch_bounds__(256) void k_out(const float* __restrict__ P,
                                             float* __restrict__ out) {
  __shared__ float ps[2][520];
  const size_t SL = (size_t)4096 * 520;
  const int t    = threadIdx.x;
  const int half = t >> 7, lt = t & 127;
  const int i    = blockIdx.x * 2 + half;
  const float* pr = P + (size_t)i * 520;
  for (int q = lt; q < 520; q += 128) ps[half][q] = pr[q] + pr[SL + q];
  __syncthreads();
  for (int c = lt; c < 512; c += 128) {           // c = u*8 + h
    int u = c >> 3, hd = c & 7;
    float o = ps[half][hd * 64 + u] / ps[half][512 + hd];
    out[(size_t)i * 512 + c] = fmaxf(o, 0.f);
  }
}

extern "C" void kernel_launch(void* const* d_in, const int* in_sizes, int n_in,
                              void* d_out, int out_size, void* d_ws, size_t ws_size,
                              hipStream_t stream) {
  const float* X  = (const float*)d_in[0];
  const float* A  = (const float*)d_in[1];
  const float* W  = (const float*)d_in[2];
  const float* av = (const float*)d_in[3];
  float* out = (float*)d_out;
  char*  ws  = (char*)d_ws;

  float* P   = (float*)ws;                 // 2 slabs x 4096 x 520 fp32
  u16*   Gtp = (u16*)(ws + 17039360);      // 256*17 tiles * 1024 B

  k_hg<<<dim3(128, 4), 256, 0, stream>>>(X, W, av, Gtp);
  k_gemm<<<512, 512, 0, stream>>>(A, Gtp, P);
  k_out<<<2048, 256, 0, stream>>>(P, out);
}

// Round 8
// 144.407 us; speedup vs baseline: 1.1705x; 1.0574x over previous
//
#include <hip/hip_runtime.h>

// GraphAttentionLayer: B=1, N=4096, F=256, H=8, U=64
//
// e_src cancels in softmax over j =>
//   out[i, u*8+h] = relu( (A @ (w*h))[i, h*64+u] / (A @ w)[i, h] ),  w = exp(e_dst)
// => ONE dense GEMM  C = A(4096x4096) x G(4096x544), G = [w*h (512) | w (8) | 0 (24)]
//
// R11: k_hg -> matrix cores. R10 left k_gemm at 45.5us but totals say
// k_hg+k_out ~ 100us; k_hg's fp32 VALU GEMM is LDS-bound (~1.07 GB LDS
// traffic) + barrier-bound. Replace with split-bf16 3-pass MFMA
// (x=xh+xl, w=wh+wl; keep xh*wh+xh*wl+xl*wh -> rel err ~1e-5, fp32-grade):
//  k_pre: X(4096x256), W(256x512) fp32 -> hi/lo bf16 in MFMA-frag 1KB tiles
//         (Gtp-style: tile*1024B + lane*16B, lane&31 = row/col, lane>>5*8+i = k).
//  k_hg:  pure MFMA: per wave 16 k-tiles x {4-8 indep 16B loads + 3 MFMA},
//         NO LDS staging, NO barriers in K loop (R5-R10-proven ILP shape).
//         e_dst via half-wave shfl_xor butterfly on the fp32 acc; exp/scale/
//         Gtp-store code paths verbatim from the proven kernel.
//  k_gemm/k_out: frozen (R10).
//
// Gtp layout (HW-verified R4): tile (tk=k>>4, nt=n>>5), id=tk*17+nt, 1024 B:
//   u16[ id*512 + ((n&31) + 32*((k&15)>>3))*8 + (k&7) ]
//
// ws: P 2 slabs (17,039,360 B; Xp-hi/lo alias its first 4 MB, dead before
//     k_gemm writes P) | Gtp @17039360 (4,456,448 B) | Wp-hi @21495808
//     (262,144 B) | Wp-lo @21757952 (262,144 B). Total 22,020,096 B.

typedef unsigned short u16;
typedef unsigned int   u32;
typedef __attribute__((ext_vector_type(8)))  short  short8;    // 8 bf16 (4 VGPR)
typedef __attribute__((ext_vector_type(16))) float  floatx16;  // 32x32 MFMA acc
typedef __attribute__((ext_vector_type(8)))  unsigned short u16x8;
typedef __attribute__((ext_vector_type(4)))  unsigned short u16x4;

__device__ __forceinline__ u16 f2bf(float x) {
  u32 u = __float_as_uint(x);
  u += 0x7fffu + ((u >> 16) & 1u);   // RNE
  return (u16)(u >> 16);
}
__device__ __forceinline__ float bf2f(u16 h) {
  return __uint_as_float((u32)h << 16);
}

// ---------------------------------------------------------------------------
// Kernel 0: X,W fp32 -> hi/lo bf16 in MFMA-frag tile layout.
//  Xp: tile (mt 0..127, kt 0..15) id = mt*16+kt, data[lane*8+i] =
//      X[mt*32+(lane&31)][kt*16+(lane>>5)*8+i]
//  Wp: tile (ct 0..15, kt 0..15) id = ct*16+kt, data[lane*8+i] =
//      W[kt*16+(lane>>5)*8+i][ct*32+(lane&31)]
// Grid 576 x 256: b<512 -> X (131072 thr = 2048 tiles x 64), else W (256x64).
// ---------------------------------------------------------------------------
__global__ __launch_bounds__(256) void k_pre(const float* __restrict__ X,
                                             const float* __restrict__ W,
                                             u16* __restrict__ Xph, u16* __restrict__ Xpl,
                                             u16* __restrict__ Wph, u16* __restrict__ Wpl) {
  const int b = blockIdx.x, t = threadIdx.x;
  float xv[8];
  u16* dh; u16* dl; size_t doff;
  if (b < 512) {
    int tid  = b * 256 + t;
    int tile = tid >> 6, lane = tid & 63;
    int j = (tile >> 4) * 32 + (lane & 31);
    int k = (tile & 15) * 16 + (lane >> 5) * 8;
    const float* xp = X + (size_t)j * 256 + k;
    float4 v0 = *(const float4*)xp;
    float4 v1 = *(const float4*)(xp + 4);
    xv[0]=v0.x; xv[1]=v0.y; xv[2]=v0.z; xv[3]=v0.w;
    xv[4]=v1.x; xv[5]=v1.y; xv[6]=v1.z; xv[7]=v1.w;
    dh = Xph; dl = Xpl; doff = (size_t)tile * 512 + lane * 8;
  } else {
    int tid  = (b - 512) * 256 + t;
    int tile = tid >> 6, lane = tid & 63;
    int c = (tile >> 4) * 32 + (lane & 31);
    int k = (tile & 15) * 16 + (lane >> 5) * 8;
#pragma unroll
    for (int i = 0; i < 8; ++i) xv[i] = W[(size_t)(k + i) * 512 + c];
    dh = Wph; dl = Wpl; doff = (size_t)tile * 512 + lane * 8;
  }
  u16x8 hi, lo;
#pragma unroll
  for (int i = 0; i < 8; ++i) {
    u16 h = f2bf(xv[i]);
    hi[i] = h;
    lo[i] = f2bf(xv[i] - bf2f(h));
  }
  *(u16x8*)(dh + doff) = hi;
  *(u16x8*)(dl + doff) = lo;
}

// ---------------------------------------------------------------------------
// Kernel 1: h = X@W via split-bf16 3-pass MFMA, e_dst -> w = exp, write Gtp.
// Block: 256 thr = 4 waves, 32 j x 128 c (2 whole heads; wave wn: n-tile
// ct = y*4+wn, head_local = wn>>1). Per k-tile: 4 indep global loads (L2-hot
// frag tiles) + 3 MFMA; 2 acc chains (kt parity); no LDS staging/barriers in
// the K loop. e: p = h*ad, butterfly over half-wave (32 cols), atomicAdd into
// eL; exp; scale acc; scatter bf16 to Gtp. Grid (128, 4) = 512 blocks = 2/CU.
// ---------------------------------------------------------------------------
__global__ __launch_bounds__(256) void k_hg(const u16* __restrict__ Xph,
                                            const u16* __restrict__ Xpl,
                                            const u16* __restrict__ Wph,
                                            const u16* __restrict__ Wpl,
                                            const float* __restrict__ av,
                                            u16* __restrict__ Gtp) {
  __shared__ float eL[64];    // [j_local*2 + head_local]
  __shared__ float w8L[64];
  const int t    = threadIdx.x;
  const int bx   = blockIdx.x;         // m-tile (32 j)
  const int y    = blockIdx.y;         // heads 2y, 2y+1
  const int j0   = bx * 32;
  const int wn   = t >> 6, lane = t & 63;
  const int ml   = lane & 31, kh = lane >> 5;
  const int ct   = y * 4 + wn;
  const int c    = ct * 32 + ml;       // global col (0..511)
  const int hl   = wn >> 1;            // head_local 0/1

  if (t < 64) eL[t] = 0.f;
  __syncthreads();

  floatx16 a0, a1;
#pragma unroll
  for (int r = 0; r < 16; ++r) { a0[r] = 0.f; a1[r] = 0.f; }

  const u16* xh = Xph + (size_t)(bx * 16) * 512 + lane * 8;
  const u16* xl = Xpl + (size_t)(bx * 16) * 512 + lane * 8;
  const u16* wh = Wph + (size_t)(ct * 16) * 512 + lane * 8;
  const u16* wl = Wpl + (size_t)(ct * 16) * 512 + lane * 8;

#pragma unroll
  for (int kt = 0; kt < 16; kt += 2) {
    short8 fxh0 = *(const short8*)(xh + (size_t)kt * 512);
    short8 fxl0 = *(const short8*)(xl + (size_t)kt * 512);
    short8 fwh0 = *(const short8*)(wh + (size_t)kt * 512);
    short8 fwl0 = *(const short8*)(wl + (size_t)kt * 512);
    short8 fxh1 = *(const short8*)(xh + (size_t)(kt + 1) * 512);
    short8 fxl1 = *(const short8*)(xl + (size_t)(kt + 1) * 512);
    short8 fwh1 = *(const short8*)(wh + (size_t)(kt + 1) * 512);
    short8 fwl1 = *(const short8*)(wl + (size_t)(kt + 1) * 512);
    a0 = __builtin_amdgcn_mfma_f32_32x32x16_bf16(fxh0, fwh0, a0, 0, 0, 0);
    a1 = __builtin_amdgcn_mfma_f32_32x32x16_bf16(fxh1, fwh1, a1, 0, 0, 0);
    a0 = __builtin_amdgcn_mfma_f32_32x32x16_bf16(fxh0, fwl0, a0, 0, 0, 0);
    a1 = __builtin_amdgcn_mfma_f32_32x32x16_bf16(fxh1, fwl1, a1, 0, 0, 0);
    a0 = __builtin_amdgcn_mfma_f32_32x32x16_bf16(fxl0, fwh0, a0, 0, 0, 0);
    a1 = __builtin_amdgcn_mfma_f32_32x32x16_bf16(fxl1, fwh1, a1, 0, 0, 0);
  }
  floatx16 hacc;
#pragma unroll
  for (int r = 0; r < 16; ++r) hacc[r] = a0[r] + a1[r];

  // e_dst partials: p[r] = h * a_dst[c&63]; butterfly over the 32-lane half
  // (cols of this n-tile); rows are identical across a half for fixed r.
  {
    const float ad = av[64 + (c & 63)];
    float p[16];
#pragma unroll
    for (int r = 0; r < 16; ++r) p[r] = hacc[r] * ad;
#pragma unroll
    for (int m = 1; m <= 16; m <<= 1)
#pragma unroll
      for (int r = 0; r < 16; ++r) p[r] += __shfl_xor(p[r], m);
    if (ml == 0) {
#pragma unroll
      for (int r = 0; r < 16; ++r) {
        int jl = (r & 3) + 8 * (r >> 2) + 4 * kh;
        atomicAdd(&eL[jl * 2 + hl], p[r]);
      }
    }
  }
  __syncthreads();
  if (t < 64) {
    float e = fminf(30.f, fmaxf(-30.f, eL[t]));
    w8L[t] = __expf(e);
  }
  __syncthreads();

  // scale by w and scatter bf16 into Gtp B-frag layout
  // C/D: col = lane&31 (= c), row jl = (r&3)+8*(r>>2)+4*kh
#pragma unroll
  for (int r = 0; r < 16; ++r) {
    int jl = (r & 3) + 8 * (r >> 2) + 4 * kh;
    int j  = j0 + jl;
    float g = hacc[r] * w8L[jl * 2 + hl];
    Gtp[(size_t)((j >> 4) * 17 + ct) * 512 + ((c & 31) + 32 * ((j & 15) >> 3)) * 8 + (j & 7)] =
        f2bf(g);
  }
  // den rows (n = 512 + h, this block's 2 heads x 32 rows)
  if (t < 64) {
    int jj = t >> 1, lh2 = t & 1, h = 2 * y + lh2, j = j0 + jj;
    Gtp[(size_t)((j >> 4) * 17 + 16) * 512 + (h + 32 * ((jj & 15) >> 3)) * 8 + (jj & 7)] =
        f2bf(w8L[jj * 2 + lh2]);
  }
  // zero pad (n in [520,544)): slots [8,32) and [40,64) of tile nt=16; y==3 does it
  if (y == 3 && t < 96) {
    int tk2 = t / 48, r = t - tk2 * 48;
    int slot = (r < 24) ? (8 + r) : (16 + r);
    u16x8 z = {0, 0, 0, 0, 0, 0, 0, 0};
    *(u16x8*)(Gtp + (size_t)(((j0 >> 4) + tk2) * 17 + 16) * 512 + slot * 8) = z;
  }
}

// ---------------------------------------------------------------------------
// Kernel 2: Pz = A(fp32,{0,1}) x G^T via 32x32x16 bf16 MFMA, PLAIN stores.
// (R10-proven: BM=32, N-split, wave owns 1 n-tile, 4 indep B-loads + 4 A
// ds_reads + 4 MFMA per ds-iter, Z=2, XCD-pinned, launch_bounds(512,4).)
// ---------------------------------------------------------------------------
__global__ __launch_bounds__(512, 4) void k_gemm(const float* __restrict__ A,
                                                 const u16* __restrict__ Gtp,
                                                 float* __restrict__ P) {
  __shared__ __align__(16) u16 As[2][32 * 256];  // 2 x 16 KB
  const int t    = threadIdx.x;
  const int bid  = blockIdx.x;
  const int xcd  = bid & 7, seq = bid >> 3;      // HW round-robins blockIdx%8 -> XCD
  const int z    = xcd >> 2;                     // k-slice, constant per XCD
  const int idx  = ((xcd & 3) << 6) + seq;       // 0..255 per z
  const int strip = idx >> 1;                    // 0..127
  const int nh   = idx & 1;                      // n-half
  const int i0   = strip * 32;
  const int kt0  = z * 2048;
  const int w    = t >> 6, lane = t & 63;
  const int ml   = lane & 31, kh = lane >> 5;
  const int nt   = nh * 8 + w;                   // this wave's n-tile

  floatx16 c0, dn;
#pragma unroll
  for (int r = 0; r < 16; ++r) { c0[r] = 0.f; dn[r] = 0.f; }

  // A staging: thread -> row ar (0..31), q-th float4 at k = (t&15)*4 + q*64
  const int ar  = t >> 4;
  const int af  = (t & 15) * 4;
  const float* pa = A + (size_t)(i0 + ar) * 4096 + kt0 + af;
  const int sbase = ar * 256 + (t & 1) * 4;   // + swizzled granule*8
  const int scb   = (t & 15) >> 1;            // granule = q*8 + scb
  const int arx   = ar & 7;

  // A-frag reads: row m = ml, granule g -> physical g^(ml&7); k-tile j <-> granule 2j+kh
  const int arow = ml * 256;
  const int mx   = ml & 7;

  float4 areg[4];
#pragma unroll
  for (int q = 0; q < 4; ++q) areg[q] = *(const float4*)(pa + q * 64);
#pragma unroll
  for (int q = 0; q < 4; ++q) {
    u16x4 v = {f2bf(areg[q].x), f2bf(areg[q].y), f2bf(areg[q].z), f2bf(areg[q].w)};
    *(u16x4*)(&As[0][sbase + ((q * 8 + scb) ^ arx) * 8]) = v;
  }
  __syncthreads();

  for (int cc = 0; cc < 8; ++cc) {
    const int cb = cc & 1;
    if (cc < 7) {                    // prefetch next chunk early (hidden by compute)
#pragma unroll
      for (int q = 0; q < 4; ++q)
        areg[q] = *(const float4*)(pa + (cc + 1) * 256 + q * 64);
    }
    const int ktb = (kt0 >> 4) + cc * 16;
#pragma unroll 2
    for (int ds = 0; ds < 4; ++ds) {
      short8 b0 = *(const short8*)(Gtp + (size_t)((ktb + ds * 4 + 0) * 17 + nt) * 512 + lane * 8);
      short8 b1 = *(const short8*)(Gtp + (size_t)((ktb + ds * 4 + 1) * 17 + nt) * 512 + lane * 8);
      short8 b2 = *(const short8*)(Gtp + (size_t)((ktb + ds * 4 + 2) * 17 + nt) * 512 + lane * 8);
      short8 b3 = *(const short8*)(Gtp + (size_t)((ktb + ds * 4 + 3) * 17 + nt) * 512 + lane * 8);
      short8 a0 = *(const short8*)(&As[cb][arow + ((ds * 8 + 0 + kh) ^ mx) * 8]);
      short8 a1 = *(const short8*)(&As[cb][arow + ((ds * 8 + 2 + kh) ^ mx) * 8]);
      short8 a2 = *(const short8*)(&As[cb][arow + ((ds * 8 + 4 + kh) ^ mx) * 8]);
      short8 a3 = *(const short8*)(&As[cb][arow + ((ds * 8 + 6 + kh) ^ mx) * 8]);
      c0 = __builtin_amdgcn_mfma_f32_32x32x16_bf16(a0, b0, c0, 0, 0, 0);
      c0 = __builtin_amdgcn_mfma_f32_32x32x16_bf16(a1, b1, c0, 0, 0, 0);
      c0 = __builtin_amdgcn_mfma_f32_32x32x16_bf16(a2, b2, c0, 0, 0, 0);
      c0 = __builtin_amdgcn_mfma_f32_32x32x16_bf16(a3, b3, c0, 0, 0, 0);
    }
    // den tile 16: wave covers k-tiles {2w, 2w+1} of this chunk (nh==0 only)
    if (nh == 0) {
      short8 e0 = *(const short8*)(Gtp + (size_t)((ktb + w * 2) * 17 + 16) * 512 + lane * 8);
      short8 e1 = *(const short8*)(Gtp + (size_t)((ktb + w * 2 + 1) * 17 + 16) * 512 + lane * 8);
      short8 a0 = *(const short8*)(&As[cb][arow + ((w * 4 + kh) ^ mx) * 8]);
      short8 a1 = *(const short8*)(&As[cb][arow + ((w * 4 + 2 + kh) ^ mx) * 8]);
      dn = __builtin_amdgcn_mfma_f32_32x32x16_bf16(a0, e0, dn, 0, 0, 0);
      dn = __builtin_amdgcn_mfma_f32_32x32x16_bf16(a1, e1, dn, 0, 0, 0);
    }
    if (cc < 7) {
      __syncthreads();               // readers of other buffer done
#pragma unroll
      for (int q = 0; q < 4; ++q) {
        u16x4 v = {f2bf(areg[q].x), f2bf(areg[q].y), f2bf(areg[q].z), f2bf(areg[q].w)};
        *(u16x4*)(&As[cb ^ 1][sbase + ((q * 8 + scb) ^ arx) * 8]) = v;
      }
      __syncthreads();               // writes visible
    }
  }

  // ---- epilogue: plain stores to slab z (no atomics) ----
  float* Pz = P + (size_t)z * (4096 * 520);
  const int col0 = nt * 32 + ml;
  // C/D layout: col = lane&31, row = (r&3) + 8*(r>>2) + 4*(lane>>5)
#pragma unroll
  for (int r = 0; r < 16; ++r) {
    int row = i0 + 4 * kh + (r & 3) + 8 * (r >> 2);
    Pz[(size_t)row * 520 + col0] = c0[r];
  }

  // den cols 512..519: reduce dn across the 8 waves via LDS (As[0] free:
  // last read in chunk cc==6, all waves past that barrier).
  if (nh == 0) {
    float* dred = (float*)&As[0][0];   // 8 waves x 32 rows x 8 cols = 8 KB
    if (ml < 8) {
#pragma unroll
      for (int r = 0; r < 16; ++r) {
        int row32 = 4 * kh + (r & 3) + 8 * (r >> 2);
        dred[(w * 32 + row32) * 8 + ml] = dn[r];
      }
    }
    __syncthreads();
    if (t < 256) {
      int row = t >> 3, c = t & 7;   // 32 rows x 8 cols
      float s = 0.f;
#pragma unroll
      for (int ww = 0; ww < 8; ++ww) s += dred[(ww * 32 + row) * 8 + c];
      Pz[(size_t)(i0 + row) * 520 + 512 + c] = s;
    }
  }
}

// ---------------------------------------------------------------------------
// Kernel 3: out[i, u*8+h] = relu( SUMz Pz[i][h*64+u] / SUMz Pz[i][512+h] ).
// 2 rows/block, 2048 blocks.
// ---------------------------------------------------------------------------
__global__ __launch_bounds__(256) void k_out(const float* __restrict__ P,
                                             float* __restrict__ out) {
  __shared__ float ps[2][520];
  const size_t SL = (size_t)4096 * 520;
  const int t    = threadIdx.x;
  const int half = t >> 7, lt = t & 127;
  const int i    = blockIdx.x * 2 + half;
  const float* pr = P + (size_t)i * 520;
  for (int q = lt; q < 520; q += 128) ps[half][q] = pr[q] + pr[SL + q];
  __syncthreads();
  for (int c = lt; c < 512; c += 128) {           // c = u*8 + h
    int u = c >> 3, hd = c & 7;
    float o = ps[half][hd * 64 + u] / ps[half][512 + hd];
    out[(size_t)i * 512 + c] = fmaxf(o, 0.f);
  }
}

extern "C" void kernel_launch(void* const* d_in, const int* in_sizes, int n_in,
                              void* d_out, int out_size, void* d_ws, size_t ws_size,
                              hipStream_t stream) {
  const float* X  = (const float*)d_in[0];
  const float* A  = (const float*)d_in[1];
  const float* W  = (const float*)d_in[2];
  const float* av = (const float*)d_in[3];
  float* out = (float*)d_out;
  char*  ws  = (char*)d_ws;

  float* P   = (float*)ws;                  // 2 slabs x 4096 x 520 fp32
  u16*   Xph = (u16*)ws;                    // aliases P[0:2MB)  (dead before k_gemm)
  u16*   Xpl = (u16*)(ws + 2097152);        // aliases P[2MB:4MB)
  u16*   Gtp = (u16*)(ws + 17039360);       // 256*17 tiles * 1024 B
  u16*   Wph = (u16*)(ws + 21495808);       // 256 tiles * 1024 B
  u16*   Wpl = (u16*)(ws + 21757952);       // 256 tiles * 1024 B

  k_pre<<<576, 256, 0, stream>>>(X, W, Xph, Xpl, Wph, Wpl);
  k_hg<<<dim3(128, 4), 256, 0, stream>>>(Xph, Xpl, Wph, Wpl, av, Gtp);
  k_gemm<<<512, 512, 0, stream>>>(A, Gtp, P);
  k_out<<<2048, 256, 0, stream>>>(P, out);
}